// Round 1
// baseline (2315.597 us; speedup 1.0000x reference)
//
#include <hip/hip_runtime.h>
#include <cstdint>
#include <cstddef>

typedef unsigned short u16;
typedef __attribute__((ext_vector_type(8))) short short8;
typedef __attribute__((ext_vector_type(4))) float f32x4;

#define XT_HSTRIDE 18432      /* 2*36*256 */
#define XT_BSTRIDE 1308672    /* 71*18432 */
#define K_TOT 20736
#define N_TOT 32768

__device__ __forceinline__ u16 f2bf(float f) {
  uint32_t u = __builtin_bit_cast(uint32_t, f);
  u = (u + 0x7fffu + ((u >> 16) & 1u)) >> 16;
  return (u16)u;
}
__device__ __forceinline__ float bf2f(u16 h) {
  uint32_t u = ((uint32_t)h) << 16;
  return __builtin_bit_cast(float, u);
}

// ---- pack weights: Wb[m][pos*256+c] = bf16(W[m][c][kh][kw]) ----
__global__ __launch_bounds__(256) void pack_w(const float* __restrict__ W,
                                              u16* __restrict__ Wb) {
  __shared__ u16 wl[20736];
  const int m = blockIdx.x;
  const int t = threadIdx.x;
  const size_t base = (size_t)m * K_TOT;
  for (int i = t; i < K_TOT; i += 256) {
    float f = W[base + i];          // input layout per m: (c, pos), i = c*81+pos
    int c = i / 81;
    int pos = i - c * 81;
    wl[pos * 256 + c] = f2bf(f);
  }
  __syncthreads();
  for (int i = t; i < K_TOT; i += 256) Wb[base + i] = wl[i];
}

// ---- pack x: xT[b][h][par][j][c] = bf16(x[b][c][h][2j+par]) ----
__global__ __launch_bounds__(256) void pack_x(const float* __restrict__ X,
                                              u16* __restrict__ xT) {
  __shared__ u16 xl[256 * 73];
  const int h = blockIdx.x;   // 0..70
  const int b = blockIdx.y;   // 0..31
  const int t = threadIdx.x;  // = c on write phase
  for (int i = t; i < 256 * 71; i += 256) {
    int c = i / 71;
    int w = i - c * 71;
    float f = X[(((size_t)(b * 256 + c)) * 71 + h) * 71 + w];
    xl[c * 73 + w] = f2bf(f);
  }
  __syncthreads();
  const size_t obase = (size_t)b * XT_BSTRIDE + (size_t)h * XT_HSTRIDE;
  for (int s = 0; s < 71; ++s) {
    int par = (s >= 36) ? 1 : 0;
    int j = s - par * 36;
    int w = 2 * j + par;
    xT[obase + par * 9216 + j * 256 + t] = xl[t * 73 + w];
  }
}

// ---- conv as implicit GEMM: U[m][n] = sum_k Wb[m][k] * X[n][k] ----
// n = b*1024 + hp*32 + wp ; k = (kh*9+kw)*256 + c
__global__ __launch_bounds__(256) void conv_gemm(const u16* __restrict__ Wb,
                                                 const u16* __restrict__ xT,
                                                 u16* __restrict__ U) {
  __shared__ __align__(16) u16 As[128 * 32];
  __shared__ __align__(16) u16 Bs[128 * 32];
  const int tid = threadIdx.x;
  const int bx = blockIdx.x;
  const int m0 = (bx & 7) * 128;
  const int n0 = (bx >> 3) * 128;
  const int lane = tid & 63;
  const int wave = tid >> 6;
  const int wm = wave >> 1;   // 0..1
  const int wn = wave & 1;    // 0..1

  // staging: 2 slots/thread per tile; slot -> (row = sr or 64+sr, 8-elem chunk sq)
  const int sr = tid >> 2;
  const int sq = (tid & 3) * 8;

  const u16* aP0 = Wb + (size_t)(m0 + sr) * K_TOT + sq;
  const u16* aP1 = Wb + (size_t)(m0 + 64 + sr) * K_TOT + sq;
  const int ldsS0 = sr * 32 + sq;
  const int ldsS1 = (64 + sr) * 32 + sq;

  const int n_a = n0 + sr;
  const int n_b = n0 + 64 + sr;
  const size_t nb0 = (size_t)(n_a >> 10) * XT_BSTRIDE +
                     (size_t)(((n_a >> 5) & 31) * 2) * XT_HSTRIDE + (size_t)(n_a & 31) * 256;
  const size_t nb1 = (size_t)(n_b >> 10) * XT_BSTRIDE +
                     (size_t)(((n_b >> 5) & 31) * 2) * XT_HSTRIDE + (size_t)(n_b & 31) * 256;
  const u16* bP0 = xT + nb0 + sq;
  const u16* bP1 = xT + nb1 + sq;

  f32x4 acc[4][4];
#pragma unroll
  for (int i = 0; i < 4; ++i)
#pragma unroll
    for (int j = 0; j < 4; ++j) acc[i][j] = (f32x4){0.f, 0.f, 0.f, 0.f};

  // fragment offset: row = lane&15 within 16-row tile, 8 contiguous k at quad*8
  const int frow = (lane & 15) * 32 + (lane >> 4) * 8;

  for (int kh = 0; kh < 9; ++kh) {
    for (int kw = 0; kw < 9; ++kw) {
      const int koffA = (kh * 9 + kw) * 256;
      const int koffB = kh * XT_HSTRIDE + (kw & 1) * 9216 + (kw >> 1) * 256;
      for (int c0 = 0; c0 < 256; c0 += 32) {
        uint4 a0 = *(const uint4*)(aP0 + koffA + c0);
        uint4 a1 = *(const uint4*)(aP1 + koffA + c0);
        uint4 b0 = *(const uint4*)(bP0 + koffB + c0);
        uint4 b1 = *(const uint4*)(bP1 + koffB + c0);
        __syncthreads();
        *(uint4*)&As[ldsS0] = a0;
        *(uint4*)&As[ldsS1] = a1;
        *(uint4*)&Bs[ldsS0] = b0;
        *(uint4*)&Bs[ldsS1] = b1;
        __syncthreads();
        short8 af[4], bfv[4];
#pragma unroll
        for (int i = 0; i < 4; ++i) {
          af[i]  = *(const short8*)&As[(wm * 64 + i * 16) * 32 + frow];
          bfv[i] = *(const short8*)&Bs[(wn * 64 + i * 16) * 32 + frow];
        }
#pragma unroll
        for (int i = 0; i < 4; ++i)
#pragma unroll
          for (int j = 0; j < 4; ++j)
            acc[i][j] = __builtin_amdgcn_mfma_f32_16x16x32_bf16(af[i], bfv[j], acc[i][j], 0, 0, 0);
      }
    }
  }

  // C/D layout: col = lane&15, row = (lane>>4)*4 + reg   [measured m89/m91]
  const int r0 = (lane >> 4) * 4;
  const int cn = lane & 15;
#pragma unroll
  for (int i = 0; i < 4; ++i) {
#pragma unroll
    for (int j = 0; j < 4; ++j) {
      const int mg = m0 + wm * 64 + i * 16 + r0;
      const int ng = n0 + wn * 64 + j * 16 + cn;
#pragma unroll
      for (int r = 0; r < 4; ++r)
        U[(size_t)(mg + r) * N_TOT + ng] = f2bf(acc[i][j][r]);
    }
  }
}

// ---- dynamic routing: one block per (b,hp); thread = (nc,oc) ----
__global__ __launch_bounds__(1024) void routing_k(const u16* __restrict__ U,
                                                  const float* __restrict__ bias,
                                                  float* __restrict__ out) {
  const int t = threadIdx.x;       // m = nc*32 + oc
  const int bx = blockIdx.x;
  const int b = bx >> 5;
  const int hp = bx & 31;
  const int oc = t & 31;
  const int nc = t >> 5;
  __shared__ float sm[1024];

  float u_r[32];
  {
    const uint4* up4 = (const uint4*)(U + (size_t)t * N_TOT + b * 1024 + hp * 32);
    const float bs = bias[t];
#pragma unroll
    for (int i = 0; i < 4; ++i) {
      uint4 q = up4[i];
      uint32_t vv[4] = {q.x, q.y, q.z, q.w};
#pragma unroll
      for (int k = 0; k < 4; ++k) {
        u_r[i * 8 + k * 2]     = bf2f((u16)(vv[k] & 0xffffu)) + bs;
        u_r[i * 8 + k * 2 + 1] = bf2f((u16)(vv[k] >> 16)) + bs;
      }
    }
  }

  float bij = 0.f;
  float s[32];
  float scale = 0.f;

  for (int it = 0; it < 3; ++it) {
    sm[t] = bij;
    __syncthreads();
    // softmax over nc for this oc (values are small; no max-subtract needed)
    float den = 0.f;
#pragma unroll
    for (int i = 0; i < 32; ++i) den += __expf(sm[i * 32 + oc]);
    const float c = __expf(bij) / den;
    // s[nc][wp] = sum_oc c*u_hat : butterfly allreduce across the 32-lane oc group
#pragma unroll
    for (int w = 0; w < 32; ++w) s[w] = c * u_r[w];
#pragma unroll
    for (int off = 1; off < 32; off <<= 1) {
#pragma unroll
      for (int w = 0; w < 32; ++w) s[w] += __shfl_xor(s[w], off, 64);
    }
    // squash over wp
    float n2 = 0.f;
#pragma unroll
    for (int w = 0; w < 32; ++w) n2 += s[w] * s[w];
    scale = sqrtf(n2) / (1.f + n2);
    if (it < 2) {
      // b_ij += sum_wp u_hat * v ;  v = scale*s
      float agr = 0.f;
#pragma unroll
      for (int w = 0; w < 32; ++w) agr += u_r[w] * s[w];
      bij += scale * agr;
    }
    __syncthreads();
  }

  // lane oc writes element wp==oc (register-select to avoid scratch)
  float val = s[0];
#pragma unroll
  for (int i = 1; i < 32; ++i) val = (oc == i) ? s[i] : val;
  out[(size_t)((b * 32 + nc) * 32 + hp) * 32 + oc] = scale * val;
}

extern "C" void kernel_launch(void* const* d_in, const int* in_sizes, int n_in,
                              void* d_out, int out_size, void* d_ws, size_t ws_size,
                              hipStream_t stream) {
  const float* x = (const float*)d_in[0];
  const float* W = (const float*)d_in[1];
  const float* bias = (const float*)d_in[2];

  // workspace layout (bytes): Wb 42,467,328 | xT 83,755,008 | U 67,108,864  (total 193.3 MB)
  u16* Wb = (u16*)d_ws;
  u16* xT = (u16*)((char*)d_ws + 42467328u);
  u16* U  = (u16*)((char*)d_ws + 126222336u);
  float* out = (float*)d_out;

  pack_w<<<dim3(1024), dim3(256), 0, stream>>>(W, Wb);
  pack_x<<<dim3(71, 32), dim3(256), 0, stream>>>(x, xT);
  conv_gemm<<<dim3(2048), dim3(256), 0, stream>>>(Wb, xT, U);
  routing_k<<<dim3(1024), dim3(1024), 0, stream>>>(U, bias, out);
}